// Round 14
// baseline (52494.403 us; speedup 1.0000x reference)
//
#include <hip/hip_runtime.h>
#include <hip/hip_fp16.h>

typedef _Float16 f16;
typedef _Float16 f16x2 __attribute__((ext_vector_type(2)));
typedef _Float16 f16x8 __attribute__((ext_vector_type(8)));
typedef float f32x4 __attribute__((ext_vector_type(4)));
typedef unsigned int u32;

#define BATCH 32
#define SEQT  2048
#define DIN   256
#define HU    256
#define G4    1024          // 4*H
#define MROWS (BATCH*SEQT)  // 65536

// ---- workspace layout (bytes) ----
// xw   f16 [65536][1024] @ 0            134217728
// xh   f16 [65536][256]  @ 134217728     33554432
// wt   f16 [1024][256]   @ 167772160       524288
// upk4 u32 [32][1024][4] @ 168296448       524288   (chunk-major U)
#define WS_XW 0
#define WS_XH 134217728UL
#define WS_WT 167772160UL
#define WS_UP 168296448UL
#define WS_NEED 168820736UL

// ---------------- prep kernels ----------------
__global__ void pack_u(const float* __restrict__ U, u32* __restrict__ upk4) {
    int idx = blockIdx.x * 256 + threadIdx.x;      // 128*1024
    int p = idx >> 10, j = idx & 1023;
    f16x2 h;
    h.x = (f16)U[(2 * p) * G4 + j];
    h.y = (f16)U[(2 * p + 1) * G4 + j];
    upk4[(((p >> 2) * 1024 + j) << 2) + (p & 3)] = __builtin_bit_cast(u32, h);
}

__global__ void conv_x(const float* __restrict__ x, f16* __restrict__ xh) {
    int idx = blockIdx.x * 256 + threadIdx.x;      // 65536*32
    int row = idx >> 5, c = idx & 31;
    const float4* src = (const float4*)(x + row * 256 + c * 8);
    float4 v0 = src[0], v1 = src[1];
    f16x8 o;
    o[0] = (f16)v0.x; o[1] = (f16)v0.y; o[2] = (f16)v0.z; o[3] = (f16)v0.w;
    o[4] = (f16)v1.x; o[5] = (f16)v1.y; o[6] = (f16)v1.z; o[7] = (f16)v1.w;
    *(f16x8*)(xh + row * 256 + c * 8) = o;
}

__global__ void conv_w(const float* __restrict__ W, f16* __restrict__ wt) {
    int idx = blockIdx.x * 256 + threadIdx.x;      // 1024*32
    int j = idx >> 5, c = idx & 31;
    f16x8 o;
#pragma unroll
    for (int i = 0; i < 8; ++i) o[i] = (f16)W[(c * 8 + i) * G4 + j];
    *(f16x8*)(wt + j * 256 + c * 8) = o;
}

// ---------------- xW GEMM: [65536,256]x[256,1024] fp16 MFMA ----------------
__launch_bounds__(256)
__global__ void gemm_xw(const f16* __restrict__ xh, const f16* __restrict__ wt,
                        const float* __restrict__ bias, f16* __restrict__ xw) {
    __shared__ __align__(16) f16 As[128 * 256];   // 64 KB, swizzled chunks
    __shared__ __align__(16) f16 Bs[128 * 256];   // 64 KB
    int mt = blockIdx.x, nt = blockIdx.y;
    int t = threadIdx.x, lane = t & 63, w = t >> 6;

    const uint4* Ag = (const uint4*)(xh + (size_t)mt * 128 * 256);
    const uint4* Bg = (const uint4*)(wt + (size_t)nt * 128 * 256);
#pragma unroll
    for (int i = 0; i < 16; ++i) {
        int o16 = t + i * 256;            // 16B chunk id 0..4095
        int row = o16 >> 5, c = o16 & 31;
        uint4 va = Ag[o16];
        uint4 vb = Bg[o16];
        int sw = c ^ (row & 7);
        *(uint4*)((char*)As + row * 512 + sw * 16) = va;
        *(uint4*)((char*)Bs + row * 512 + sw * 16) = vb;
    }
    __syncthreads();

    int wr = w >> 1, wc = w & 1;
    f32x4 acc[4][4];
#pragma unroll
    for (int mi = 0; mi < 4; ++mi)
#pragma unroll
        for (int ni = 0; ni < 4; ++ni) acc[mi][ni] = (f32x4){0.f, 0.f, 0.f, 0.f};

    int rA = lane & 15;
    int kg = lane >> 4;    // 0..3 -> k-offset group of 8
#pragma unroll
    for (int ks = 0; ks < 8; ++ks) {
        f16x8 af[4], bf[4];
#pragma unroll
        for (int mi = 0; mi < 4; ++mi) {
            int row = wr * 64 + mi * 16 + rA;
            int c = ks * 4 + kg;
            af[mi] = *(const f16x8*)((const char*)As + row * 512 + ((c ^ (row & 7)) * 16));
        }
#pragma unroll
        for (int ni = 0; ni < 4; ++ni) {
            int row = wc * 64 + ni * 16 + rA;
            int c = ks * 4 + kg;
            bf[ni] = *(const f16x8*)((const char*)Bs + row * 512 + ((c ^ (row & 7)) * 16));
        }
#pragma unroll
        for (int mi = 0; mi < 4; ++mi)
#pragma unroll
            for (int ni = 0; ni < 4; ++ni)
                acc[mi][ni] = __builtin_amdgcn_mfma_f32_16x16x32_f16(af[mi], bf[ni], acc[mi][ni], 0, 0, 0);
    }

    // epilogue: C/D layout col=lane&15, row=(lane>>4)*4+q
    int r4 = (lane >> 4) * 4, cc = lane & 15;
    float bv[4];
#pragma unroll
    for (int ni = 0; ni < 4; ++ni) bv[ni] = bias[nt * 128 + wc * 64 + ni * 16 + cc];
#pragma unroll
    for (int mi = 0; mi < 4; ++mi)
#pragma unroll
        for (int ni = 0; ni < 4; ++ni)
#pragma unroll
            for (int q = 0; q < 4; ++q) {
                int grow = mt * 128 + wr * 64 + mi * 16 + r4 + q;
                int gcol = nt * 128 + wc * 64 + ni * 16 + cc;
                xw[(size_t)grow * 1024 + gcol] = (f16)(acc[mi][ni][q] + bv[ni]);
            }
}

// ---------------- recurrence ----------------
__device__ __forceinline__ float fdot2u(u32 u, u32 h, float acc) {
    return __builtin_amdgcn_fdot2(__builtin_bit_cast(f16x2, u),
                                  __builtin_bit_cast(f16x2, h), acc, false);
}
__device__ __forceinline__ float sigm(float x) {
    return 1.0f / (1.0f + __expf(-x));
}
__device__ __forceinline__ float tanh_f(float x) {
    x = fminf(fmaxf(x, -15.0f), 15.0f);
    float e = __expf(2.0f * x);
    return (e - 1.0f) / (e + 1.0f);
}

// ---- R14 = R6 structure x 2 batches per WG (stream amortization) ----
// Ledger from R6/R8/R12/R13: step time == streamed-U-bytes / ~78 B/cyc
// per CU (R6: 368 KB -> 4730 cyc; R13: 512 KB, latency-serialized ->
// 9100). Instruction count (R8) and pipelining tricks (R12: spills at
// the immovable 64-VGPR grant) don't move it. Only bytes/batch do.
// Here each WG serves TWO batches: every streamed uint4 feeds 8 fdot2
// (4/batch) -> per-batch stream halves with zero new synchronization.
// 16 WGs x 1024 thr; thread t = column t, dual accumulator chains.
// Update: threads 0..255 own (batch0, unit t), 256..511 (batch1, u-256)
// — t>>8 wave-uniform. 9 chunks stay in LDS stride-36 (0 conflicts),
// 23 streamed, exactly R6's proven split. LDS total 156.5 KB.

__launch_bounds__(1024)
__global__ void lstm_rec(const uint4* __restrict__ upk4, const f16* __restrict__ xw,
                         float* __restrict__ out) {
    __shared__ __align__(16) u32 ulds[1024 * 36];  // 144 KB: chunks 23..31, stride 36
    __shared__ __align__(16) u32 hpair[256];       // h pairs: [0..127] b0, [128..255] b1
    __shared__ __align__(16) float gbuf[2048];     // gates: [0..1023] b0, [1024..2047] b1

    int b0 = blockIdx.x * 2, t = threadIdx.x;

#pragma unroll
    for (int ch = 0; ch < 9; ++ch) {
        uint4 v = upk4[(23 + ch) * 1024 + t];
        *(uint4*)&ulds[t * 36 + ch * 4] = v;
    }
    if (t < 256) hpair[t] = 0u;

    float c_state = 0.0f;                          // (t<512) state for its (batch,unit)
    const f16* xp0 = xw + (size_t)b0 * SEQT * G4;
    const f16* xp1 = xp0 + (size_t)SEQT * G4;
    float* op0 = out + (size_t)b0 * SEQT * HU;
    float* op1 = op0 + (size_t)SEQT * HU;
    f16 xa0 = xp0[t], xa1 = xp1[t];
    __syncthreads();

    for (int st = 0; st < SEQT; ++st) {
        float a0 = (float)xa0, a1 = 0.f, a2 = 0.f, a3 = 0.f;
        float e0 = (float)xa1, e1 = 0.f, e2 = 0.f, e3 = 0.f;
        if (st < SEQT - 1) { xa0 = xp0[G4 + t]; xa1 = xp1[G4 + t]; }
        xp0 += G4; xp1 += G4;

        // 23 streamed chunks: one uint4 load feeds both batches
#pragma unroll
        for (int c = 0; c < 23; ++c) {
            uint4 u4 = upk4[c * 1024 + t];
            uint4 h0 = *(const uint4*)&hpair[c << 2];
            uint4 h1 = *(const uint4*)&hpair[128 + (c << 2)];
            a0 = fdot2u(u4.x, h0.x, a0);  e0 = fdot2u(u4.x, h1.x, e0);
            a1 = fdot2u(u4.y, h0.y, a1);  e1 = fdot2u(u4.y, h1.y, e1);
            a2 = fdot2u(u4.z, h0.z, a2);  e2 = fdot2u(u4.z, h1.z, e2);
            a3 = fdot2u(u4.w, h0.w, a3);  e3 = fdot2u(u4.w, h1.w, e3);
        }
        // 9 LDS chunks
#pragma unroll
        for (int ch = 0; ch < 9; ++ch) {
            uint4 u4 = *(const uint4*)&ulds[t * 36 + ch * 4];
            uint4 h0 = *(const uint4*)&hpair[(23 + ch) << 2];
            uint4 h1 = *(const uint4*)&hpair[128 + ((23 + ch) << 2)];
            a0 = fdot2u(u4.x, h0.x, a0);  e0 = fdot2u(u4.x, h1.x, e0);
            a1 = fdot2u(u4.y, h0.y, a1);  e1 = fdot2u(u4.y, h1.y, e1);
            a2 = fdot2u(u4.z, h0.z, a2);  e2 = fdot2u(u4.z, h1.z, e2);
            a3 = fdot2u(u4.w, h0.w, a3);  e3 = fdot2u(u4.w, h1.w, e3);
        }
        float A = (a0 + a1) + (a2 + a3);
        float E = (e0 + e1) + (e2 + e3);

        // activation: gate = t>>8 (wave-uniform); g-gate (2) is tanh
        int gate = t >> 8;
        float actA = (gate == 2) ? tanh_f(A) : sigm(A);
        float actE = (gate == 2) ? tanh_f(E) : sigm(E);
        gbuf[t] = actA;
        gbuf[1024 + t] = actE;
        __syncthreads();

        // c/h update: t<256 -> batch0 unit t; 256<=t<512 -> batch1 unit t-256
        if (t < 512) {
            int bb = t >> 8;                        // wave-uniform
            int u = t & 255;
            const float* gb = &gbuf[bb << 10];
            float gi = gb[u];
            float gf = gb[256 + u];
            float gg = gb[512 + u];
            float go = gb[768 + u];
            c_state = gf * c_state + gi * gg;
            float h = go * tanh_f(c_state);
            (bb ? op1 : op0)[u] = h;
            ((f16*)hpair)[(bb << 8) + u] = (f16)h;
        }
        op0 += HU; op1 += HU;
        __syncthreads();
    }
}

extern "C" void kernel_launch(void* const* d_in, const int* in_sizes, int n_in,
                              void* d_out, int out_size, void* d_ws, size_t ws_size,
                              hipStream_t stream) {
    const float* x    = (const float*)d_in[0];
    const float* W    = (const float*)d_in[1];
    const float* U    = (const float*)d_in[2];
    const float* bias = (const float*)d_in[3];
    float* out = (float*)d_out;

    if (ws_size < WS_NEED) return;  // fail loudly rather than corrupt
    char* ws = (char*)d_ws;
    f16* xw    = (f16*)(ws + WS_XW);
    f16* xh    = (f16*)(ws + WS_XH);
    f16* wt    = (f16*)(ws + WS_WT);
    u32* upk4  = (u32*)(ws + WS_UP);

    pack_u<<<512, 256, 0, stream>>>(U, upk4);
    conv_x<<<8192, 256, 0, stream>>>(x, xh);
    conv_w<<<128, 256, 0, stream>>>(W, wt);
    gemm_xw<<<dim3(512, 8), 256, 0, stream>>>(xh, wt, bias, xw);
    lstm_rec<<<16, 1024, 0, stream>>>((const uint4*)upk4, xw, out);
}